// Round 1
// baseline (3503.645 us; speedup 1.0000x reference)
//
#include <hip/hip_runtime.h>
#include <math.h>

#define TT 1024
#define DD 128
#define UU 64

__device__ __forceinline__ float sigm(float x) {
    return 1.0f / (1.0f + __expf(-x));
}
__device__ __forceinline__ float tanhfast(float x) {
    float e = __expf(2.0f * x);
    return 1.0f - 2.0f / (e + 1.0f);
}

// One workgroup per batch element. 256 threads = 4 waves.
// Thread tid owns z-column tid (gate g = tid>>6, unit n = tid&63).
// Wave w owns gate w -> LayerNorm over 64 units == wave-wide shfl reduction.
// Wave 0 performs the cell update (needs all 4 gates per unit) via LDS exchange.
__global__ __launch_bounds__(256, 1)
void lstm_fused(const float* __restrict__ obss,
                const float* __restrict__ W1,
                const float* __restrict__ gamma1, const float* __restrict__ beta1,
                const float* __restrict__ gc1, const float* __restrict__ bc1,
                const float* __restrict__ W2,
                const float* __restrict__ gamma2, const float* __restrict__ beta2,
                const float* __restrict__ gc2, const float* __restrict__ bc2,
                const float* __restrict__ Wd, const float* __restrict__ bd,
                float* __restrict__ out)
{
    const int tid  = threadIdx.x;      // 0..255
    const int b    = blockIdx.x;       // batch element
    const int lane = tid & 63;
    const int wav  = tid >> 6;         // gate index of this column

    __shared__ __align__(16) float xbuf[2][DD];
    __shared__ __align__(16) float h1s[UU];
    __shared__ __align__(16) float h2s[UU];
    __shared__ __align__(16) float zs[256];
    __shared__ __align__(16) float h2hist[16 * UU];
    __shared__ __align__(16) float wds[UU * 16];
    __shared__ float bds[16];

    // ---- weights into registers (column tid of each matrix) ----
    float w1x[DD];  // W1 rows 0..127   (input part)
    float w1h[UU];  // W1 rows 128..191 (recurrent part)
    float w2x[UU];  // W2 rows 0..63    (h1 input part)
    float w2h[UU];  // W2 rows 64..127  (h2 recurrent part)
    #pragma unroll
    for (int k = 0; k < DD; ++k) w1x[k] = W1[k * 256 + tid];
    #pragma unroll
    for (int k = 0; k < UU; ++k) w1h[k] = W1[(DD + k) * 256 + tid];
    #pragma unroll
    for (int k = 0; k < UU; ++k) w2x[k] = W2[k * 256 + tid];
    #pragma unroll
    for (int k = 0; k < UU; ++k) w2h[k] = W2[(UU + k) * 256 + tid];

    const float g1  = gamma1[tid], bb1 = beta1[tid];
    const float g2  = gamma2[tid], bb2 = beta2[tid];
    const float gcl1 = gc1[lane], bcl1 = bc1[lane];
    const float gcl2 = gc2[lane], bcl2 = bc2[lane];

    for (int i = tid; i < UU * 16; i += 256) wds[i] = Wd[i];
    if (tid < 16) bds[tid] = bd[tid];
    if (tid < UU) { h1s[tid] = 0.0f; h2s[tid] = 0.0f; }

    const float* xrow = obss + (size_t)b * TT * DD;
    if (tid < DD) xbuf[0][tid] = xrow[tid];   // stage x(0)

    float c1 = 0.0f, c2 = 0.0f;
    __syncthreads();

    #pragma unroll 1
    for (int t = 0; t < TT; ++t) {
        // ---- prefetch x(t+1) into register (latency hidden under A+B) ----
        float xn = 0.0f;
        if (tid < DD) {
            int tn = t + 1;
            if (tn < TT) xn = xrow[(size_t)tn * DD + tid];
        }

        // ================= Phase A: z1 = x @ W1x + h1 @ W1h =================
        const float4* xb  = (const float4*)xbuf[t & 1];
        const float4* h1v = (const float4*)h1s;
        float a0 = 0.f, a1 = 0.f, a2 = 0.f, a3 = 0.f;
        #pragma unroll
        for (int k4 = 0; k4 < DD / 4; ++k4) {
            float4 xv = xb[k4];
            a0 = fmaf(xv.x, w1x[4 * k4 + 0], a0);
            a1 = fmaf(xv.y, w1x[4 * k4 + 1], a1);
            a2 = fmaf(xv.z, w1x[4 * k4 + 2], a2);
            a3 = fmaf(xv.w, w1x[4 * k4 + 3], a3);
        }
        #pragma unroll
        for (int k4 = 0; k4 < UU / 4; ++k4) {
            float4 hv = h1v[k4];
            a0 = fmaf(hv.x, w1h[4 * k4 + 0], a0);
            a1 = fmaf(hv.y, w1h[4 * k4 + 1], a1);
            a2 = fmaf(hv.z, w1h[4 * k4 + 2], a2);
            a3 = fmaf(hv.w, w1h[4 * k4 + 3], a3);
        }
        float z = (a0 + a1) + (a2 + a3);

        // LN over the 64 lanes of this wave (one gate per wave)
        float s = z, q = z * z;
        #pragma unroll
        for (int m = 1; m < 64; m <<= 1) {
            s += __shfl_xor(s, m, 64);
            q += __shfl_xor(q, m, 64);
        }
        float mu  = s * (1.0f / 64.0f);
        float var = q * (1.0f / 64.0f) - mu * mu;
        float zn  = (z - mu) * rsqrtf(var + 1e-12f) * g1 + bb1;

        float act;
        if (wav == 1)      act = tanhfast(zn);       // j
        else if (wav == 2) act = sigm(zn + 1.0f);    // f (+1 bias)
        else               act = sigm(zn);           // i, o
        zs[tid] = act;
        __syncthreads();                             // (1)

        // ================= Phase B: cell 1 (wave 0) =========================
        if (wav == 0) {
            float ai = zs[lane], aj = zs[64 + lane];
            float af = zs[128 + lane], ao = zs[192 + lane];
            c1 = c1 * af + ai * aj;
            float cs = c1, cq = c1 * c1;
            #pragma unroll
            for (int m = 1; m < 64; m <<= 1) {
                cs += __shfl_xor(cs, m, 64);
                cq += __shfl_xor(cq, m, 64);
            }
            float cmu  = cs * (1.0f / 64.0f);
            float cvar = cq * (1.0f / 64.0f) - cmu * cmu;
            float cn   = (c1 - cmu) * rsqrtf(cvar + 1e-12f) * gcl1 + bcl1;
            h1s[lane]  = tanhfast(cn) * ao;
        }
        __syncthreads();                             // (2)

        // ================= Phase C: z2 = h1 @ W2x + h2 @ W2h ================
        const float4* h1r = (const float4*)h1s;
        const float4* h2r = (const float4*)h2s;
        float d0 = 0.f, d1 = 0.f, d2 = 0.f, d3 = 0.f;
        #pragma unroll
        for (int k4 = 0; k4 < UU / 4; ++k4) {
            float4 hv = h1r[k4];
            d0 = fmaf(hv.x, w2x[4 * k4 + 0], d0);
            d1 = fmaf(hv.y, w2x[4 * k4 + 1], d1);
            d2 = fmaf(hv.z, w2x[4 * k4 + 2], d2);
            d3 = fmaf(hv.w, w2x[4 * k4 + 3], d3);
        }
        #pragma unroll
        for (int k4 = 0; k4 < UU / 4; ++k4) {
            float4 hv = h2r[k4];
            d0 = fmaf(hv.x, w2h[4 * k4 + 0], d0);
            d1 = fmaf(hv.y, w2h[4 * k4 + 1], d1);
            d2 = fmaf(hv.z, w2h[4 * k4 + 2], d2);
            d3 = fmaf(hv.w, w2h[4 * k4 + 3], d3);
        }
        float z2 = (d0 + d1) + (d2 + d3);

        float s2 = z2, q2 = z2 * z2;
        #pragma unroll
        for (int m = 1; m < 64; m <<= 1) {
            s2 += __shfl_xor(s2, m, 64);
            q2 += __shfl_xor(q2, m, 64);
        }
        float mu2  = s2 * (1.0f / 64.0f);
        float var2 = q2 * (1.0f / 64.0f) - mu2 * mu2;
        float zn2  = (z2 - mu2) * rsqrtf(var2 + 1e-12f) * g2 + bb2;

        float act2;
        if (wav == 1)      act2 = tanhfast(zn2);
        else if (wav == 2) act2 = sigm(zn2 + 1.0f);
        else               act2 = sigm(zn2);
        zs[tid] = act2;

        // stage prefetched x(t+1) into the other LDS buffer
        if (tid < DD) xbuf[(t + 1) & 1][tid] = xn;
        __syncthreads();                             // (3)

        // ================= Phase D: cell 2 (wave 0) =========================
        if (wav == 0) {
            float ai = zs[lane], aj = zs[64 + lane];
            float af = zs[128 + lane], ao = zs[192 + lane];
            c2 = c2 * af + ai * aj;
            float cs = c2, cq = c2 * c2;
            #pragma unroll
            for (int m = 1; m < 64; m <<= 1) {
                cs += __shfl_xor(cs, m, 64);
                cq += __shfl_xor(cq, m, 64);
            }
            float cmu  = cs * (1.0f / 64.0f);
            float cvar = cq * (1.0f / 64.0f) - cmu * cmu;
            float cn   = (c2 - cmu) * rsqrtf(cvar + 1e-12f) * gcl2 + bcl2;
            float h2v  = tanhfast(cn) * ao;
            h2s[lane]  = h2v;
            h2hist[(t & 15) * UU + lane] = h2v;
        }
        __syncthreads();                             // (4)

        // ============ batched output projection every 16 steps ==============
        if ((t & 15) == 15) {
            int rloc = tid >> 4;   // local row 0..15
            int a    = tid & 15;   // output column 0..15
            float o = bds[a];
            #pragma unroll
            for (int k = 0; k < UU; ++k)
                o = fmaf(h2hist[rloc * UU + k], wds[k * 16 + a], o);
            int r = t - 15 + rloc;
            out[((size_t)b * TT + r) * 16 + a] = tanhfast(o);
            __syncthreads();                         // (5) protect h2hist
        }
    }
}

extern "C" void kernel_launch(void* const* d_in, const int* in_sizes, int n_in,
                              void* d_out, int out_size, void* d_ws, size_t ws_size,
                              hipStream_t stream) {
    (void)in_sizes; (void)n_in; (void)d_ws; (void)ws_size; (void)out_size;
    const float* obss   = (const float*)d_in[0];
    const float* W1     = (const float*)d_in[1];
    const float* gamma1 = (const float*)d_in[2];
    const float* beta1  = (const float*)d_in[3];
    const float* gc1    = (const float*)d_in[4];
    const float* bc1    = (const float*)d_in[5];
    const float* W2     = (const float*)d_in[6];
    const float* gamma2 = (const float*)d_in[7];
    const float* beta2  = (const float*)d_in[8];
    const float* gc2    = (const float*)d_in[9];
    const float* bc2    = (const float*)d_in[10];
    const float* Wd     = (const float*)d_in[11];
    const float* bd     = (const float*)d_in[12];
    float* out = (float*)d_out;

    lstm_fused<<<256, 256, 0, stream>>>(obss, W1, gamma1, beta1, gc1, bc1,
                                        W2, gamma2, beta2, gc2, bc2, Wd, bd, out);
}

// Round 2
// 3017.007 us; speedup vs baseline: 1.1613x; 1.1613x over previous
//
#include <hip/hip_runtime.h>
#include <math.h>

#define TT 1024
#define DD 128
#define UU 64

__device__ __forceinline__ float sigm(float x) {
    return 1.0f / (1.0f + __expf(-x));
}
__device__ __forceinline__ float tanhfast(float x) {
    float e = __expf(2.0f * x);
    return 1.0f - 2.0f / (e + 1.0f);
}

// ================= x-part GEMM: z1x[r, col] = obss[b, t0+tloc, :] @ W1[0:128, col]
// r = b*CH + tloc enumerates [b][tloc] contiguously. 64 rows per block.
__global__ __launch_bounds__(256, 1)
void xgemm(const float* __restrict__ obss, const float* __restrict__ W1,
           float* __restrict__ z1x, int t0, int chsh)
{
    const int tid = threadIdx.x;
    const int CH = 1 << chsh;
    __shared__ __align__(16) float xs[64 * DD];

    const int rbase = blockIdx.x * 64;
    for (int i = tid; i < 64 * (DD / 4); i += 256) {
        int rr = i >> 5;           // DD/4 == 32 float4 per row
        int k4 = i & 31;
        int r  = rbase + rr;
        int b  = r >> chsh;
        int tl = r & (CH - 1);
        ((float4*)xs)[rr * 32 + k4] =
            ((const float4*)(obss + ((size_t)b * TT + t0 + tl) * DD))[k4];
    }

    float w[DD];
    #pragma unroll
    for (int k = 0; k < DD; ++k) w[k] = W1[k * 256 + tid];
    __syncthreads();

    for (int rr = 0; rr < 64; rr += 2) {
        float a0=0,a1=0,a2=0,a3=0, b0=0,b1=0,b2=0,b3=0;
        const float4* x0 = (const float4*)(xs + rr * DD);
        const float4* x1 = (const float4*)(xs + (rr + 1) * DD);
        #pragma unroll
        for (int k4 = 0; k4 < DD / 4; ++k4) {
            float4 xv = x0[k4], yv = x1[k4];
            a0 = fmaf(xv.x, w[4*k4+0], a0);
            a1 = fmaf(xv.y, w[4*k4+1], a1);
            a2 = fmaf(xv.z, w[4*k4+2], a2);
            a3 = fmaf(xv.w, w[4*k4+3], a3);
            b0 = fmaf(yv.x, w[4*k4+0], b0);
            b1 = fmaf(yv.y, w[4*k4+1], b1);
            b2 = fmaf(yv.z, w[4*k4+2], b2);
            b3 = fmaf(yv.w, w[4*k4+3], b3);
        }
        size_t r = (size_t)rbase + rr;
        z1x[r * 256 + tid]       = (a0 + a1) + (a2 + a3);
        z1x[(r + 1) * 256 + tid] = (b0 + b1) + (b2 + b3);
    }
}

// ================= recurrent kernel: one block per batch element ==============
// Thread tid owns z-column tid (gate = tid>>6, unit = tid&63); wave = gate.
// Cell updates are computed REDUNDANTLY by all 4 waves; each wave keeps a
// private LDS copy of h1/h2 (wave-synchronous, no barrier for own-copy RAW).
// Only 2 __syncthreads per step (gate exchange zsA / zsB).
__global__ __launch_bounds__(256, 1)
void lstm_rec(const float* __restrict__ z1x,
              const float* __restrict__ W1, const float* __restrict__ W2,
              const float* __restrict__ gamma1, const float* __restrict__ beta1,
              const float* __restrict__ gc1, const float* __restrict__ bc1,
              const float* __restrict__ gamma2, const float* __restrict__ beta2,
              const float* __restrict__ gc2, const float* __restrict__ bc2,
              const float* __restrict__ Wd, const float* __restrict__ bd,
              float* __restrict__ out, float* __restrict__ state,
              int t0, int nsteps)
{
    const int tid  = threadIdx.x;
    const int b    = blockIdx.x;
    const int lane = tid & 63;
    const int wav  = tid >> 6;

    __shared__ __align__(16) float zsA[256], zsB[256];
    __shared__ __align__(16) float h1p[4][UU], h2p[4][UU];
    __shared__ __align__(16) float h2hist[16 * 65];   // stride 65: no bank conflict
    __shared__ __align__(16) float wds[UU * 16];
    __shared__ float bds[16];

    float w1h[UU], w2x[UU], w2h[UU];
    #pragma unroll
    for (int k = 0; k < UU; ++k) w1h[k] = W1[(DD + k) * 256 + tid];
    #pragma unroll
    for (int k = 0; k < UU; ++k) w2x[k] = W2[k * 256 + tid];
    #pragma unroll
    for (int k = 0; k < UU; ++k) w2h[k] = W2[(UU + k) * 256 + tid];

    const float g1  = gamma1[tid], bb1 = beta1[tid];
    const float g2  = gamma2[tid], bb2 = beta2[tid];
    const float gcl1 = gc1[lane], bcl1 = bc1[lane];
    const float gcl2 = gc2[lane], bcl2 = bc2[lane];

    for (int i = tid; i < UU * 16; i += 256) wds[i] = Wd[i];
    if (tid < 16) bds[tid] = bd[tid];

    float c1, c2;
    if (t0 == 0) {
        c1 = 0.f; c2 = 0.f;
        h1p[wav][lane] = 0.f;
        h2p[wav][lane] = 0.f;
    } else {
        const float* st = state + (size_t)b * 256;
        c1 = st[lane];
        c2 = st[128 + lane];
        h1p[wav][lane] = st[64 + lane];
        h2p[wav][lane] = st[192 + lane];
    }
    float h1v = 0.f, h2v = 0.f;

    const float* zrow = z1x + (size_t)b * nsteps * 256;
    float zx = zrow[tid];
    __syncthreads();

    #pragma unroll 1
    for (int tl = 0; tl < nsteps; ++tl) {
        // prefetch next step's z1x (consumed at loop end)
        int tnl = (tl + 1 < nsteps) ? tl + 1 : tl;
        float zxn = zrow[(size_t)tnl * 256 + tid];

        // ---- Phase A: z1 = z1x + h1 @ W1h, LN, gate activation ----
        float a0=0,a1=0,a2=0,a3=0;
        const float4* hv4 = (const float4*)h1p[wav];
        #pragma unroll
        for (int k4 = 0; k4 < UU / 4; ++k4) {
            float4 hv = hv4[k4];
            a0 = fmaf(hv.x, w1h[4*k4+0], a0);
            a1 = fmaf(hv.y, w1h[4*k4+1], a1);
            a2 = fmaf(hv.z, w1h[4*k4+2], a2);
            a3 = fmaf(hv.w, w1h[4*k4+3], a3);
        }
        float z = zx + (a0 + a1) + (a2 + a3);
        float s = z, q = z * z;
        #pragma unroll
        for (int m = 1; m < 64; m <<= 1) {
            s += __shfl_xor(s, m, 64);
            q += __shfl_xor(q, m, 64);
        }
        float mu  = s * (1.f/64.f);
        float var = q * (1.f/64.f) - mu * mu;
        float zn  = (z - mu) * rsqrtf(var + 1e-12f) * g1 + bb1;
        float act = (wav == 1) ? tanhfast(zn)
                  : (wav == 2) ? sigm(zn + 1.f)
                  :              sigm(zn);
        zsA[tid] = act;
        __syncthreads();                                  // (1)

        // ---- Phase B: cell 1 (all waves redundantly) ----
        {
            float ai = zsA[lane],      aj = zsA[64 + lane];
            float af = zsA[128 + lane], ao = zsA[192 + lane];
            c1 = c1 * af + ai * aj;
            float cs = c1, cq = c1 * c1;
            #pragma unroll
            for (int m = 1; m < 64; m <<= 1) {
                cs += __shfl_xor(cs, m, 64);
                cq += __shfl_xor(cq, m, 64);
            }
            float cmu  = cs * (1.f/64.f);
            float cvar = cq * (1.f/64.f) - cmu * cmu;
            float cn   = (c1 - cmu) * rsqrtf(cvar + 1e-12f) * gcl1 + bcl1;
            h1v = tanhfast(cn) * ao;
            h1p[wav][lane] = h1v;     // own-wave copy, no barrier needed
        }

        // ---- Phase C: z2 = h1 @ W2x + h2 @ W2h, LN, activation ----
        float d0=0,d1=0,d2=0,d3=0;
        const float4* h1r = (const float4*)h1p[wav];
        const float4* h2r = (const float4*)h2p[wav];
        #pragma unroll
        for (int k4 = 0; k4 < UU / 4; ++k4) {
            float4 hv = h1r[k4];
            d0 = fmaf(hv.x, w2x[4*k4+0], d0);
            d1 = fmaf(hv.y, w2x[4*k4+1], d1);
            d2 = fmaf(hv.z, w2x[4*k4+2], d2);
            d3 = fmaf(hv.w, w2x[4*k4+3], d3);
        }
        #pragma unroll
        for (int k4 = 0; k4 < UU / 4; ++k4) {
            float4 hv = h2r[k4];
            d0 = fmaf(hv.x, w2h[4*k4+0], d0);
            d1 = fmaf(hv.y, w2h[4*k4+1], d1);
            d2 = fmaf(hv.z, w2h[4*k4+2], d2);
            d3 = fmaf(hv.w, w2h[4*k4+3], d3);
        }
        float z2 = (d0 + d1) + (d2 + d3);
        float s2 = z2, q2 = z2 * z2;
        #pragma unroll
        for (int m = 1; m < 64; m <<= 1) {
            s2 += __shfl_xor(s2, m, 64);
            q2 += __shfl_xor(q2, m, 64);
        }
        float mu2  = s2 * (1.f/64.f);
        float var2 = q2 * (1.f/64.f) - mu2 * mu2;
        float zn2  = (z2 - mu2) * rsqrtf(var2 + 1e-12f) * g2 + bb2;
        float act2 = (wav == 1) ? tanhfast(zn2)
                   : (wav == 2) ? sigm(zn2 + 1.f)
                   :              sigm(zn2);
        zsB[tid] = act2;
        __syncthreads();                                  // (2)

        // ---- Phase D: cell 2 (all waves redundantly) ----
        {
            float ai = zsB[lane],       aj = zsB[64 + lane];
            float af = zsB[128 + lane], ao = zsB[192 + lane];
            c2 = c2 * af + ai * aj;
            float cs = c2, cq = c2 * c2;
            #pragma unroll
            for (int m = 1; m < 64; m <<= 1) {
                cs += __shfl_xor(cs, m, 64);
                cq += __shfl_xor(cq, m, 64);
            }
            float cmu  = cs * (1.f/64.f);
            float cvar = cq * (1.f/64.f) - cmu * cmu;
            float cn   = (c2 - cmu) * rsqrtf(cvar + 1e-12f) * gcl2 + bcl2;
            h2v = tanhfast(cn) * ao;
            h2p[wav][lane] = h2v;
            if (wav == 0) h2hist[(tl & 15) * 65 + lane] = h2v;
        }

        // ---- batched output projection every 16 steps ----
        if ((tl & 15) == 15) {
            __syncthreads();                              // h2hist visibility
            int rloc = tid >> 4;
            int a    = tid & 15;
            float o = bds[a];
            #pragma unroll
            for (int k = 0; k < UU; ++k)
                o = fmaf(h2hist[rloc * 65 + k], wds[k * 16 + a], o);
            int r = t0 + tl - 15 + rloc;
            out[((size_t)b * TT + r) * 16 + a] = tanhfast(o);
        }
        zx = zxn;
    }

    // carry state to next chunk (if any)
    if (t0 + nsteps < TT && wav == 0) {
        float* st = state + (size_t)b * 256;
        st[lane]       = c1;
        st[64 + lane]  = h1v;
        st[128 + lane] = c2;
        st[192 + lane] = h2v;
    }
}

extern "C" void kernel_launch(void* const* d_in, const int* in_sizes, int n_in,
                              void* d_out, int out_size, void* d_ws, size_t ws_size,
                              hipStream_t stream) {
    (void)in_sizes; (void)n_in; (void)out_size;
    const float* obss   = (const float*)d_in[0];
    const float* W1     = (const float*)d_in[1];
    const float* gamma1 = (const float*)d_in[2];
    const float* beta1  = (const float*)d_in[3];
    const float* gc1    = (const float*)d_in[4];
    const float* bc1    = (const float*)d_in[5];
    const float* W2     = (const float*)d_in[6];
    const float* gamma2 = (const float*)d_in[7];
    const float* beta2  = (const float*)d_in[8];
    const float* gc2    = (const float*)d_in[9];
    const float* bc2    = (const float*)d_in[10];
    const float* Wd     = (const float*)d_in[11];
    const float* bd     = (const float*)d_in[12];
    float* out = (float*)d_out;

    // ws layout: [state: 256 blocks * 256 f32][z1x chunk buffer]
    float* state = (float*)d_ws;
    float* z1x   = (float*)((char*)d_ws + (size_t)256 * 256 * sizeof(float));

    // largest chunk (power of 2, >=16) whose z1x buffer fits in ws
    int CH = 16;
    for (int c = TT; c >= 16; c >>= 1) {
        size_t need = (size_t)256 * c * 256 * sizeof(float)
                    + (size_t)256 * 256 * sizeof(float);
        if (need <= ws_size) { CH = c; break; }
    }
    int chsh = 31 - __builtin_clz((unsigned)CH);

    for (int t0 = 0; t0 < TT; t0 += CH) {
        xgemm<<<(256 * CH) / 64, 256, 0, stream>>>(obss, W1, z1x, t0, chsh);
        lstm_rec<<<256, 256, 0, stream>>>(z1x, W1, W2,
                                          gamma1, beta1, gc1, bc1,
                                          gamma2, beta2, gc2, bc2,
                                          Wd, bd, out, state, t0, CH);
    }
}

// Round 3
// 2017.071 us; speedup vs baseline: 1.7370x; 1.4957x over previous
//
#include <hip/hip_runtime.h>
#include <math.h>

#define TT 1024
#define DD 128
#define UU 64

__device__ __forceinline__ float sigm(float x) {
    return 1.0f / (1.0f + __expf(-x));
}
__device__ __forceinline__ float tanhfast(float x) {
    float e = __expf(2.0f * x);
    return 1.0f - 2.0f / (e + 1.0f);
}

// ================= x-part GEMM: z1x[r, col] = obss[b, t0+tloc, :] @ W1[0:128, col]
__global__ __launch_bounds__(256, 1)
void xgemm(const float* __restrict__ obss, const float* __restrict__ W1,
           float* __restrict__ z1x, int t0, int chsh)
{
    const int tid = threadIdx.x;
    const int CH = 1 << chsh;
    __shared__ __align__(16) float xs[64 * DD];

    const int rbase = blockIdx.x * 64;
    for (int i = tid; i < 64 * (DD / 4); i += 256) {
        int rr = i >> 5;
        int k4 = i & 31;
        int r  = rbase + rr;
        int b  = r >> chsh;
        int tl = r & (CH - 1);
        ((float4*)xs)[rr * 32 + k4] =
            ((const float4*)(obss + ((size_t)b * TT + t0 + tl) * DD))[k4];
    }

    float w[DD];
    #pragma unroll
    for (int k = 0; k < DD; ++k) w[k] = W1[k * 256 + tid];
    __syncthreads();

    for (int rr = 0; rr < 64; rr += 2) {
        float a0=0,a1=0,a2=0,a3=0, b0=0,b1=0,b2=0,b3=0;
        const float4* x0 = (const float4*)(xs + rr * DD);
        const float4* x1 = (const float4*)(xs + (rr + 1) * DD);
        #pragma unroll
        for (int k4 = 0; k4 < DD / 4; ++k4) {
            float4 xv = x0[k4], yv = x1[k4];
            a0 = fmaf(xv.x, w[4*k4+0], a0);
            a1 = fmaf(xv.y, w[4*k4+1], a1);
            a2 = fmaf(xv.z, w[4*k4+2], a2);
            a3 = fmaf(xv.w, w[4*k4+3], a3);
            b0 = fmaf(yv.x, w[4*k4+0], b0);
            b1 = fmaf(yv.y, w[4*k4+1], b1);
            b2 = fmaf(yv.z, w[4*k4+2], b2);
            b3 = fmaf(yv.w, w[4*k4+3], b3);
        }
        size_t r = (size_t)rbase + rr;
        z1x[r * 256 + tid]       = (a0 + a1) + (a2 + a3);
        z1x[(r + 1) * 256 + tid] = (b0 + b1) + (b2 + b3);
    }
}

// ================= recurrent kernel: layer-pipelined, 512 threads ============
// Waves 0-3 (gid 0): layer 1, step t=n.  Waves 4-7 (gid 1): layer 2, step n-1.
// h1 passes L1->L2 through a 2-slot LDS ring. 2 barriers per iteration;
// both divergent loops execute identical barrier sequences.
__global__ __launch_bounds__(512)
void lstm_rec(const float* __restrict__ z1x,
              const float* __restrict__ W1, const float* __restrict__ W2,
              const float* __restrict__ gamma1, const float* __restrict__ beta1,
              const float* __restrict__ gc1, const float* __restrict__ bc1,
              const float* __restrict__ gamma2, const float* __restrict__ beta2,
              const float* __restrict__ gc2, const float* __restrict__ bc2,
              const float* __restrict__ Wd, const float* __restrict__ bd,
              float* __restrict__ out, float* __restrict__ state,
              int t0, int nsteps)
{
    const int tid  = threadIdx.x;
    const int b    = blockIdx.x;
    const int gid  = tid >> 8;        // 0 = layer-1 group, 1 = layer-2 group
    const int stid = tid & 255;
    const int lane = stid & 63;
    const int wav  = stid >> 6;

    __shared__ __align__(16) float zsA[256], zsB[256];
    __shared__ __align__(16) float h1ring[2][UU];
    __shared__ __align__(16) float h1p[4][UU], h2p[4][UU];
    __shared__ __align__(16) float h2hist[16 * 65];
    __shared__ __align__(16) float wds[UU * 16];
    __shared__ float bds[16];

    float* st = state + (size_t)b * 256;

    if (gid == 0) {
        // =========================== LAYER 1 ===========================
        float w1h[UU];
        #pragma unroll
        for (int k = 0; k < UU; ++k) w1h[k] = W1[(DD + k) * 256 + stid];
        const float g1 = gamma1[stid], bb1 = beta1[stid];
        const float gcl = gc1[lane],  bcl = bc1[lane];
        for (int i = stid; i < UU * 16; i += 256) wds[i] = Wd[i];
        if (stid < 16) bds[stid] = bd[stid];

        float c1, h1v = 0.f;
        if (t0 == 0) { c1 = 0.f; h1p[wav][lane] = 0.f; }
        else         { c1 = st[lane]; h1v = st[64 + lane]; h1p[wav][lane] = h1v; }

        const float* zrow = z1x + (size_t)b * nsteps * 256;
        float zx = zrow[stid];
        __syncthreads();                       // (init)

        #pragma unroll 1
        for (int n = 0; n <= nsteps; ++n) {
            float zxn = zx;
            if (n < nsteps) {
                int tnl = (n + 1 < nsteps) ? n + 1 : n;
                zxn = zrow[(size_t)tnl * 256 + stid];

                float a0=0,a1=0,a2=0,a3=0;
                const float4* hv4 = (const float4*)h1p[wav];
                #pragma unroll
                for (int k4 = 0; k4 < UU / 4; ++k4) {
                    float4 hv = hv4[k4];
                    a0 = fmaf(hv.x, w1h[4*k4+0], a0);
                    a1 = fmaf(hv.y, w1h[4*k4+1], a1);
                    a2 = fmaf(hv.z, w1h[4*k4+2], a2);
                    a3 = fmaf(hv.w, w1h[4*k4+3], a3);
                }
                float z = zx + (a0 + a1) + (a2 + a3);
                float s = z, q = z * z;
                #pragma unroll
                for (int m = 1; m < 64; m <<= 1) {
                    s += __shfl_xor(s, m, 64);
                    q += __shfl_xor(q, m, 64);
                }
                float mu  = s * (1.f/64.f);
                float var = q * (1.f/64.f) - mu * mu;
                float zn  = (z - mu) * rsqrtf(var + 1e-12f) * g1 + bb1;
                zsA[stid] = (wav == 1) ? tanhfast(zn)
                          : (wav == 2) ? sigm(zn + 1.f)
                          :              sigm(zn);
            }
            // batched output projection for rows t2p-15..t2p (t2p = n-2)
            if ((n & 15) == 1 && n >= 17) {
                int t2p  = n - 2;
                int rloc = stid >> 4;
                int a    = stid & 15;
                float o = bds[a];
                #pragma unroll
                for (int k = 0; k < UU; ++k)
                    o = fmaf(h2hist[rloc * 65 + k], wds[k * 16 + a], o);
                int r = t0 + t2p - 15 + rloc;
                out[((size_t)b * TT + r) * 16 + a] = tanhfast(o);
            }
            __syncthreads();                   // B1
            if (n < nsteps) {
                float ai = zsA[lane],       aj = zsA[64 + lane];
                float af = zsA[128 + lane], ao = zsA[192 + lane];
                c1 = c1 * af + ai * aj;
                float cs = c1, cq = c1 * c1;
                #pragma unroll
                for (int m = 1; m < 64; m <<= 1) {
                    cs += __shfl_xor(cs, m, 64);
                    cq += __shfl_xor(cq, m, 64);
                }
                float cmu  = cs * (1.f/64.f);
                float cvar = cq * (1.f/64.f) - cmu * cmu;
                float cn   = (c1 - cmu) * rsqrtf(cvar + 1e-12f) * gcl + bcl;
                h1v = tanhfast(cn) * ao;
                h1p[wav][lane] = h1v;
                if (wav == 0) h1ring[n & 1][lane] = h1v;
            }
            __syncthreads();                   // B2
            zx = zxn;
        }
        // final projection: rows nsteps-16..nsteps-1
        {
            int rloc = stid >> 4;
            int a    = stid & 15;
            float o = bds[a];
            #pragma unroll
            for (int k = 0; k < UU; ++k)
                o = fmaf(h2hist[rloc * 65 + k], wds[k * 16 + a], o);
            int r = t0 + nsteps - 16 + rloc;
            out[((size_t)b * TT + r) * 16 + a] = tanhfast(o);
        }
        if (t0 + nsteps < TT && wav == 0) {
            st[lane]      = c1;
            st[64 + lane] = h1v;
        }
    } else {
        // =========================== LAYER 2 ===========================
        float w2x[UU], w2h[UU];
        #pragma unroll
        for (int k = 0; k < UU; ++k) w2x[k] = W2[k * 256 + stid];
        #pragma unroll
        for (int k = 0; k < UU; ++k) w2h[k] = W2[(UU + k) * 256 + stid];
        const float g2 = gamma2[stid], bb2 = beta2[stid];
        const float gcl = gc2[lane],  bcl = bc2[lane];

        float c2, h2v = 0.f;
        if (t0 == 0) { c2 = 0.f; h2p[wav][lane] = 0.f; }
        else         { c2 = st[128 + lane]; h2v = st[192 + lane]; h2p[wav][lane] = h2v; }
        __syncthreads();                       // (init)

        #pragma unroll 1
        for (int n = 0; n <= nsteps; ++n) {
            if (n >= 1) {
                const float4* h1r = (const float4*)h1ring[(n - 1) & 1];
                const float4* h2r = (const float4*)h2p[wav];
                float d0=0,d1=0,d2=0,d3=0;
                #pragma unroll
                for (int k4 = 0; k4 < UU / 4; ++k4) {
                    float4 hv = h1r[k4];
                    d0 = fmaf(hv.x, w2x[4*k4+0], d0);
                    d1 = fmaf(hv.y, w2x[4*k4+1], d1);
                    d2 = fmaf(hv.z, w2x[4*k4+2], d2);
                    d3 = fmaf(hv.w, w2x[4*k4+3], d3);
                }
                #pragma unroll
                for (int k4 = 0; k4 < UU / 4; ++k4) {
                    float4 hv = h2r[k4];
                    d0 = fmaf(hv.x, w2h[4*k4+0], d0);
                    d1 = fmaf(hv.y, w2h[4*k4+1], d1);
                    d2 = fmaf(hv.z, w2h[4*k4+2], d2);
                    d3 = fmaf(hv.w, w2h[4*k4+3], d3);
                }
                float z2 = (d0 + d1) + (d2 + d3);
                float s2 = z2, q2 = z2 * z2;
                #pragma unroll
                for (int m = 1; m < 64; m <<= 1) {
                    s2 += __shfl_xor(s2, m, 64);
                    q2 += __shfl_xor(q2, m, 64);
                }
                float mu2  = s2 * (1.f/64.f);
                float var2 = q2 * (1.f/64.f) - mu2 * mu2;
                float zn2  = (z2 - mu2) * rsqrtf(var2 + 1e-12f) * g2 + bb2;
                zsB[stid] = (wav == 1) ? tanhfast(zn2)
                          : (wav == 2) ? sigm(zn2 + 1.f)
                          :              sigm(zn2);
            }
            __syncthreads();                   // B1
            if (n >= 1) {
                float ai = zsB[lane],       aj = zsB[64 + lane];
                float af = zsB[128 + lane], ao = zsB[192 + lane];
                c2 = c2 * af + ai * aj;
                float cs = c2, cq = c2 * c2;
                #pragma unroll
                for (int m = 1; m < 64; m <<= 1) {
                    cs += __shfl_xor(cs, m, 64);
                    cq += __shfl_xor(cq, m, 64);
                }
                float cmu  = cs * (1.f/64.f);
                float cvar = cq * (1.f/64.f) - cmu * cmu;
                float cn   = (c2 - cmu) * rsqrtf(cvar + 1e-12f) * gcl + bcl;
                h2v = tanhfast(cn) * ao;
                h2p[wav][lane] = h2v;
                if (wav == 0) h2hist[((n - 1) & 15) * 65 + lane] = h2v;
            }
            __syncthreads();                   // B2
        }
        if (t0 + nsteps < TT && wav == 0) {
            st[128 + lane] = c2;
            st[192 + lane] = h2v;
        }
    }
}

extern "C" void kernel_launch(void* const* d_in, const int* in_sizes, int n_in,
                              void* d_out, int out_size, void* d_ws, size_t ws_size,
                              hipStream_t stream) {
    (void)in_sizes; (void)n_in; (void)out_size;
    const float* obss   = (const float*)d_in[0];
    const float* W1     = (const float*)d_in[1];
    const float* gamma1 = (const float*)d_in[2];
    const float* beta1  = (const float*)d_in[3];
    const float* gc1    = (const float*)d_in[4];
    const float* bc1    = (const float*)d_in[5];
    const float* W2     = (const float*)d_in[6];
    const float* gamma2 = (const float*)d_in[7];
    const float* beta2  = (const float*)d_in[8];
    const float* gc2    = (const float*)d_in[9];
    const float* bc2    = (const float*)d_in[10];
    const float* Wd     = (const float*)d_in[11];
    const float* bd     = (const float*)d_in[12];
    float* out = (float*)d_out;

    float* state = (float*)d_ws;
    float* z1x   = (float*)((char*)d_ws + (size_t)256 * 256 * sizeof(float));

    int CH = 16;
    for (int c = TT; c >= 16; c >>= 1) {
        size_t need = (size_t)256 * c * 256 * sizeof(float)
                    + (size_t)256 * 256 * sizeof(float);
        if (need <= ws_size) { CH = c; break; }
    }
    int chsh = 31 - __builtin_clz((unsigned)CH);

    for (int t0 = 0; t0 < TT; t0 += CH) {
        xgemm<<<(256 * CH) / 64, 256, 0, stream>>>(obss, W1, z1x, t0, chsh);
        lstm_rec<<<256, 512, 0, stream>>>(z1x, W1, W2,
                                          gamma1, beta1, gc1, bc1,
                                          gamma2, beta2, gc2, bc2,
                                          Wd, bd, out, state, t0, CH);
    }
}

// Round 4
// 1668.424 us; speedup vs baseline: 2.1000x; 1.2090x over previous
//
#include <hip/hip_runtime.h>
#include <math.h>

#define TT 1024
#define DD 128
#define UU 64

__device__ __forceinline__ float sigm(float x) {
    return 1.0f / (1.0f + __expf(-x));
}
__device__ __forceinline__ float tanhfast(float x) {
    float e = __expf(2.0f * x);
    return 1.0f - 2.0f / (e + 1.0f);
}

// DPP-based full-wave (64-lane) sum, result broadcast via readlane(63).
// Classic GCN sequence: row_shr 1/2/4/8 accumulates within 16-lane rows,
// row_bcast:15 merges row pairs, row_bcast:31 merges halves -> lane 63.
template<int CTRL>
__device__ __forceinline__ float dpp_add(float v) {
    return v + __int_as_float(__builtin_amdgcn_update_dpp(
        0, __float_as_int(v), CTRL, 0xf, 0xf, true));
}
__device__ __forceinline__ float wave_red_sum(float v) {
    v = dpp_add<0x111>(v);   // row_shr:1
    v = dpp_add<0x112>(v);   // row_shr:2
    v = dpp_add<0x114>(v);   // row_shr:4
    v = dpp_add<0x118>(v);   // row_shr:8
    v = dpp_add<0x142>(v);   // row_bcast:15
    v = dpp_add<0x143>(v);   // row_bcast:31
    return __int_as_float(__builtin_amdgcn_readlane(__float_as_int(v), 63));
}

// ================= x-part GEMM: z1x[r, col] = obss[b, t0+tloc, :] @ W1[0:128, col]
__global__ __launch_bounds__(256, 1)
void xgemm(const float* __restrict__ obss, const float* __restrict__ W1,
           float* __restrict__ z1x, int t0, int chsh)
{
    const int tid = threadIdx.x;
    const int CH = 1 << chsh;
    __shared__ __align__(16) float xs[64 * DD];

    const int rbase = blockIdx.x * 64;
    for (int i = tid; i < 64 * (DD / 4); i += 256) {
        int rr = i >> 5;
        int k4 = i & 31;
        int r  = rbase + rr;
        int b  = r >> chsh;
        int tl = r & (CH - 1);
        ((float4*)xs)[rr * 32 + k4] =
            ((const float4*)(obss + ((size_t)b * TT + t0 + tl) * DD))[k4];
    }

    float w[DD];
    #pragma unroll
    for (int k = 0; k < DD; ++k) w[k] = W1[k * 256 + tid];
    __syncthreads();

    for (int rr = 0; rr < 64; rr += 2) {
        float a0=0,a1=0,a2=0,a3=0, b0=0,b1=0,b2=0,b3=0;
        const float4* x0 = (const float4*)(xs + rr * DD);
        const float4* x1 = (const float4*)(xs + (rr + 1) * DD);
        #pragma unroll
        for (int k4 = 0; k4 < DD / 4; ++k4) {
            float4 xv = x0[k4], yv = x1[k4];
            a0 = fmaf(xv.x, w[4*k4+0], a0);
            a1 = fmaf(xv.y, w[4*k4+1], a1);
            a2 = fmaf(xv.z, w[4*k4+2], a2);
            a3 = fmaf(xv.w, w[4*k4+3], a3);
            b0 = fmaf(yv.x, w[4*k4+0], b0);
            b1 = fmaf(yv.y, w[4*k4+1], b1);
            b2 = fmaf(yv.z, w[4*k4+2], b2);
            b3 = fmaf(yv.w, w[4*k4+3], b3);
        }
        size_t r = (size_t)rbase + rr;
        z1x[r * 256 + tid]       = (a0 + a1) + (a2 + a3);
        z1x[(r + 1) * 256 + tid] = (b0 + b1) + (b2 + b3);
    }
}

// 64-float dot from an LDS vector (broadcast reads) against register weights.
__device__ __forceinline__ float dot64(const float* v, const float* w) {
    const float4* v4 = (const float4*)v;
    float a0=0,a1=0,a2=0,a3=0;
    #pragma unroll
    for (int k4 = 0; k4 < UU / 4; ++k4) {
        float4 hv = v4[k4];
        a0 = fmaf(hv.x, w[4*k4+0], a0);
        a1 = fmaf(hv.y, w[4*k4+1], a1);
        a2 = fmaf(hv.z, w[4*k4+2], a2);
        a3 = fmaf(hv.w, w[4*k4+3], a3);
    }
    return (a0 + a1) + (a2 + a3);
}

// ================= recurrent kernel: layer-pipelined, 512 threads ============
// Waves 0-3 (gid 0): layer 1 at step n; also compute z2x = h1 @ W2x in phase 2.
// Waves 4-7 (gid 1): layer 2 at step n-1; z2h = h2 @ W2h computed in phase 2
// (carried in a register), so phase 1 is just add+LN+act. 2 barriers/step.
__global__ __launch_bounds__(512, 2)
void lstm_rec(const float* __restrict__ z1x,
              const float* __restrict__ W1, const float* __restrict__ W2,
              const float* __restrict__ gamma1, const float* __restrict__ beta1,
              const float* __restrict__ gc1, const float* __restrict__ bc1,
              const float* __restrict__ gamma2, const float* __restrict__ beta2,
              const float* __restrict__ gc2, const float* __restrict__ bc2,
              const float* __restrict__ Wd, const float* __restrict__ bd,
              float* __restrict__ out, float* __restrict__ state,
              int t0, int nsteps)
{
    const int tid  = threadIdx.x;
    const int b    = blockIdx.x;
    const int gid  = tid >> 8;        // 0 = layer-1 group, 1 = layer-2 group
    const int stid = tid & 255;
    const int lane = stid & 63;
    const int wav  = stid >> 6;

    __shared__ __align__(16) float zsA[256], zsB[256], z2xs[256];
    __shared__ __align__(16) float h1p[4][UU], h2p[4][UU];
    __shared__ __align__(16) float h2hist[16 * 65];
    __shared__ __align__(16) float wds[UU * 16];
    __shared__ float bds[16];

    float* st = state + (size_t)b * 256;

    if (gid == 0) {
        // =========================== LAYER 1 (+ z2x feed) ===================
        float w1h[UU], w2x[UU];
        #pragma unroll
        for (int k = 0; k < UU; ++k) w1h[k] = W1[(DD + k) * 256 + stid];
        #pragma unroll
        for (int k = 0; k < UU; ++k) w2x[k] = W2[k * 256 + stid];
        const float g1 = gamma1[stid], bb1 = beta1[stid];
        const float gcl = gc1[lane],  bcl = bc1[lane];
        for (int i = stid; i < UU * 16; i += 256) wds[i] = Wd[i];
        if (stid < 16) bds[stid] = bd[stid];

        float c1, h1v = 0.f;
        if (t0 == 0) { c1 = 0.f; h1p[wav][lane] = 0.f; }
        else         { c1 = st[lane]; h1v = st[64 + lane]; h1p[wav][lane] = h1v; }

        const float* zrow = z1x + (size_t)b * nsteps * 256;
        float zx = zrow[stid];
        __syncthreads();                       // (init)

        #pragma unroll 1
        for (int n = 0; n <= nsteps; ++n) {
            float zxn = zx;
            if (n < nsteps) {
                int tnl = (n + 1 < nsteps) ? n + 1 : n;
                zxn = zrow[(size_t)tnl * 256 + stid];

                float z = zx + dot64(h1p[wav], w1h);
                float s = wave_red_sum(z);
                float q = wave_red_sum(z * z);
                float mu  = s * (1.f/64.f);
                float var = q * (1.f/64.f) - mu * mu;
                float zn  = (z - mu) * rsqrtf(var + 1e-12f) * g1 + bb1;
                zsA[stid] = (wav == 1) ? tanhfast(zn)
                          : (wav == 2) ? sigm(zn + 1.f)
                          :              sigm(zn);
            }
            // batched output projection for rows t2p-15..t2p (t2p = n-2)
            if ((n & 15) == 1 && n >= 17) {
                int t2p  = n - 2;
                int rloc = stid >> 4;
                int a    = stid & 15;
                float o = bds[a];
                #pragma unroll
                for (int k = 0; k < UU; ++k)
                    o = fmaf(h2hist[rloc * 65 + k], wds[k * 16 + a], o);
                int r = t0 + t2p - 15 + rloc;
                out[((size_t)b * TT + r) * 16 + a] = tanhfast(o);
            }
            __syncthreads();                   // B1
            if (n < nsteps) {
                float ai = zsA[lane],       aj = zsA[64 + lane];
                float af = zsA[128 + lane], ao = zsA[192 + lane];
                c1 = c1 * af + ai * aj;
                float cs = wave_red_sum(c1);
                float cq = wave_red_sum(c1 * c1);
                float cmu  = cs * (1.f/64.f);
                float cvar = cq * (1.f/64.f) - cmu * cmu;
                float cn   = (c1 - cmu) * rsqrtf(cvar + 1e-12f) * gcl + bcl;
                h1v = tanhfast(cn) * ao;
                h1p[wav][lane] = h1v;
                // z2x = h1(n) @ W2x  (own-wave LDS write -> read, no barrier)
                z2xs[stid] = dot64(h1p[wav], w2x);
            }
            __syncthreads();                   // B2
            zx = zxn;
        }
        // final projection: rows nsteps-16..nsteps-1
        {
            int rloc = stid >> 4;
            int a    = stid & 15;
            float o = bds[a];
            #pragma unroll
            for (int k = 0; k < UU; ++k)
                o = fmaf(h2hist[rloc * 65 + k], wds[k * 16 + a], o);
            int r = t0 + nsteps - 16 + rloc;
            out[((size_t)b * TT + r) * 16 + a] = tanhfast(o);
        }
        if (t0 + nsteps < TT && wav == 0) {
            st[lane]      = c1;
            st[64 + lane] = h1v;
        }
    } else {
        // =========================== LAYER 2 ===========================
        float w2h[UU];
        #pragma unroll
        for (int k = 0; k < UU; ++k) w2h[k] = W2[(UU + k) * 256 + stid];
        const float g2 = gamma2[stid], bb2 = beta2[stid];
        const float gcl = gc2[lane],  bcl = bc2[lane];

        float c2, h2v = 0.f;
        if (t0 == 0) { c2 = 0.f; h2p[wav][lane] = 0.f; }
        else         { c2 = st[128 + lane]; h2v = st[192 + lane]; h2p[wav][lane] = h2v; }
        // z2h carried in-register: h2(prev) @ W2h (recomputed at chunk start)
        float z2h = (t0 == 0) ? 0.f : dot64(h2p[wav], w2h);
        __syncthreads();                       // (init)

        #pragma unroll 1
        for (int n = 0; n <= nsteps; ++n) {
            if (n >= 1) {
                float z2 = z2xs[stid] + z2h;
                float s2 = wave_red_sum(z2);
                float q2 = wave_red_sum(z2 * z2);
                float mu2  = s2 * (1.f/64.f);
                float var2 = q2 * (1.f/64.f) - mu2 * mu2;
                float zn2  = (z2 - mu2) * rsqrtf(var2 + 1e-12f) * g2 + bb2;
                zsB[stid] = (wav == 1) ? tanhfast(zn2)
                          : (wav == 2) ? sigm(zn2 + 1.f)
                          :              sigm(zn2);
            }
            __syncthreads();                   // B1
            if (n >= 1) {
                float ai = zsB[lane],       aj = zsB[64 + lane];
                float af = zsB[128 + lane], ao = zsB[192 + lane];
                c2 = c2 * af + ai * aj;
                float cs = wave_red_sum(c2);
                float cq = wave_red_sum(c2 * c2);
                float cmu  = cs * (1.f/64.f);
                float cvar = cq * (1.f/64.f) - cmu * cmu;
                float cn   = (c2 - cmu) * rsqrtf(cvar + 1e-12f) * gcl + bcl;
                h2v = tanhfast(cn) * ao;
                h2p[wav][lane] = h2v;
                if (wav == 0) h2hist[((n - 1) & 15) * 65 + lane] = h2v;
                // z2h = h2(n-1) @ W2h for next step (own-wave write->read)
                z2h = dot64(h2p[wav], w2h);
            }
            __syncthreads();                   // B2
        }
        if (t0 + nsteps < TT && wav == 0) {
            st[128 + lane] = c2;
            st[192 + lane] = h2v;
        }
    }
}

extern "C" void kernel_launch(void* const* d_in, const int* in_sizes, int n_in,
                              void* d_out, int out_size, void* d_ws, size_t ws_size,
                              hipStream_t stream) {
    (void)in_sizes; (void)n_in; (void)out_size;
    const float* obss   = (const float*)d_in[0];
    const float* W1     = (const float*)d_in[1];
    const float* gamma1 = (const float*)d_in[2];
    const float* beta1  = (const float*)d_in[3];
    const float* gc1    = (const float*)d_in[4];
    const float* bc1    = (const float*)d_in[5];
    const float* W2     = (const float*)d_in[6];
    const float* gamma2 = (const float*)d_in[7];
    const float* beta2  = (const float*)d_in[8];
    const float* gc2    = (const float*)d_in[9];
    const float* bc2    = (const float*)d_in[10];
    const float* Wd     = (const float*)d_in[11];
    const float* bd     = (const float*)d_in[12];
    float* out = (float*)d_out;

    float* state = (float*)d_ws;
    float* z1x   = (float*)((char*)d_ws + (size_t)256 * 256 * sizeof(float));

    int CH = 16;
    for (int c = TT; c >= 16; c >>= 1) {
        size_t need = (size_t)256 * c * 256 * sizeof(float)
                    + (size_t)256 * 256 * sizeof(float);
        if (need <= ws_size) { CH = c; break; }
    }
    int chsh = 31 - __builtin_clz((unsigned)CH);

    for (int t0 = 0; t0 < TT; t0 += CH) {
        xgemm<<<(256 * CH) / 64, 256, 0, stream>>>(obss, W1, z1x, t0, chsh);
        lstm_rec<<<256, 512, 0, stream>>>(z1x, W1, W2,
                                          gamma1, beta1, gc1, bc1,
                                          gamma2, beta2, gc2, bc2,
                                          Wd, bd, out, state, t0, CH);
    }
}